// Round 1
// baseline (410.848 us; speedup 1.0000x reference)
//
#include <hip/hip_runtime.h>
#include <math.h>

#define BB 4096
#define LL 200
#define GD 64
#define HH 32
#define LPAD 207   // 207 % 32 = 15, gcd(15,32)=1 -> conflict-free transpose staging
#define RR 8       // rows per block in MLP kernel

// ---------------------------------------------------------------------------
// Stage 1: per-b fused  wg / ul / attention-normalized aggregation -> states
// One block per b (4096 blocks, 256 threads).
// ---------------------------------------------------------------------------
__global__ __launch_bounds__(256) void stage1_kernel(
    const float* __restrict__ gs,
    const float* __restrict__ ls,
    const float* __restrict__ W_w,
    const float* __restrict__ W_b,
    const float* __restrict__ U_w,
    const float* __restrict__ U_b,
    const float* __restrict__ att_w,
    const float* __restrict__ att_b,
    float* __restrict__ states)
{
    __shared__ float xT[64 * LPAD];   // 51.8 KB; reused as reduction buffer
    __shared__ float s_wg[HH];
    __shared__ float s_misc[2];       // [0]=g_term, [1]=s0
    __shared__ float s_V[HH + 1];     // V[0..31], S at [32]

    const int tid = threadIdx.x;
    const int b   = blockIdx.x;

    // ---- stage local_states[b] into LDS transposed: xT[d*LPAD + l] ----
    // float2 global loads (coalesced), 2-way-free LDS write pattern.
    const float2* ls2 = (const float2*)(ls + (size_t)b * (LL * 64));
    for (int i = tid; i < LL * 32; i += 256) {
        float2 v = ls2[i];
        int d2 = i & 31;      // which float2 within the row
        int l  = i >> 5;
        xT[(2 * d2 + 0) * LPAD + l] = v.x;
        xT[(2 * d2 + 1) * LPAD + l] = v.y;
    }

    // ---- wg[h] = gs[b] . W_w[h] + W_b[h]  (threads 0..31) ----
    if (tid < HH) {
        float acc = W_b[tid];
        const float* g = gs + (size_t)b * GD;
        #pragma unroll
        for (int d = 0; d < GD; ++d)
            acc += g[d] * W_w[tid * GD + d];   // g[d] wave-uniform -> s_load
        s_wg[tid] = acc;
    }
    __syncthreads();

    // ---- per-lane x column into registers (lane owns l = tid) ----
    const int lx = (tid < LL) ? tid : (LL - 1);
    float x[64];
    #pragma unroll
    for (int d = 0; d < 64; ++d)
        x[d] = xT[d * LPAD + lx];   // banks = lane%32 -> 2-way (free)

    // thread 0: g_term and s0
    if (tid == 0) {
        float gt = 0.f, t2 = 0.f;
        #pragma unroll
        for (int h = 0; h < HH; ++h) {
            gt += s_wg[h] * att_w[h];        // a_g
            t2 += s_wg[h] * att_w[HH + h];   // a_l
        }
        float lin = gt + t2 + att_b[0];
        s_misc[0] = gt;
        s_misc[1] = (lin > 0.f) ? lin : 0.01f * lin;   // leaky_relu 0.01
    }
    __syncthreads();   // xT register loads complete; s_misc ready

    // ---- ul[h] per lane; stash ul and sl in reduction buffer (alias xT) ----
    float* red = xT;   // 256*33 floats needed <= 64*207 available
    float t = 0.f;
    for (int h = 0; h < HH; ++h) {
        float acc = U_b[h];                  // uniform -> s_load
        #pragma unroll
        for (int d = 0; d < 64; ++d)
            acc += x[d] * U_w[h * 64 + d];   // U_w uniform -> s_load operand
        t += acc * att_w[HH + h];
        red[tid * 33 + h] = acc;             // bank (tid+h)%32: conflict-free
    }
    float gt  = s_misc[0];
    float lin = gt + t + att_b[0];
    float sl  = (lin > 0.f) ? lin : 0.01f * lin;
    if (tid >= LL) sl = 0.f;                 // mask padding lanes
    red[tid * 33 + 32] = sl;
    __syncthreads();

    // ---- reduce over the 256 lanes: V[h] = sum sl*ul[h], S = sum sl ----
    if (tid <= HH) {
        float s = 0.f;
        for (int tt = 0; tt < 256; ++tt) {
            float m = (tid < HH) ? red[tt * 33 + tid] : 1.f;
            s += m * red[tt * 33 + 32];
        }
        s_V[tid] = s;
    }
    __syncthreads();

    // ---- states[b] = relu(concat(n0*wg, V/total)) ----
    if (tid < 64) {
        float s0    = s_misc[1];
        float total = s0 + s_V[HH];
        float v;
        if (tid < HH) v = (s0 / total) * s_wg[tid];
        else          v = s_V[tid - HH] / total;
        states[(size_t)b * 64 + tid] = fmaxf(v, 0.f);
    }
}

// ---------------------------------------------------------------------------
// Stage 2: fused MLP 64 -> 256 -> 256 -> 8 with relu/relu/sigmoid.
// RR rows per block; thread j owns hidden unit j (weight row in VGPRs,
// activations broadcast from LDS).
// ---------------------------------------------------------------------------
__global__ __launch_bounds__(256) void mlp_kernel(
    const float* __restrict__ states,
    const float* __restrict__ l1_w, const float* __restrict__ l1_b,
    const float* __restrict__ l2_w, const float* __restrict__ l2_b,
    const float* __restrict__ l3_w, const float* __restrict__ l3_b,
    float* __restrict__ out)
{
    __shared__ __align__(16) float s_x [RR * 64];
    __shared__ __align__(16) float s_a1[RR * 256];
    __shared__ float s_a2[RR * 257];   // pad 257 -> conflict-free layer-3 reads

    const int tid = threadIdx.x;
    const int b0  = blockIdx.x * RR;

    // load states tile (RR*64 floats) via float4
    const float4* st4 = (const float4*)(states + (size_t)b0 * 64);
    if (tid < RR * 16) ((float4*)s_x)[tid] = st4[tid];
    __syncthreads();

    float w[64];

    // ---- layer 1: a1[r][j] = relu(states[r] . l1_w[j] + l1_b[j]) ----
    {
        const float* wr = l1_w + tid * 64;
        #pragma unroll
        for (int d = 0; d < 64; ++d) w[d] = wr[d];
        float bias = l1_b[tid];
        #pragma unroll
        for (int r = 0; r < RR; ++r) {
            float acc = bias;
            #pragma unroll
            for (int d = 0; d < 64; ++d)
                acc += s_x[r * 64 + d] * w[d];   // broadcast, merges to b128
            s_a1[r * 256 + tid] = fmaxf(acc, 0.f);
        }
    }
    __syncthreads();

    // ---- layer 2: a2[r][j] = relu(a1[r] . l2_w[j] + l2_b[j]) ----
    {
        float acc[RR];
        float bias = l2_b[tid];
        #pragma unroll
        for (int r = 0; r < RR; ++r) acc[r] = bias;
        for (int kc = 0; kc < 4; ++kc) {
            const float* wr = l2_w + tid * 256 + kc * 64;
            #pragma unroll
            for (int d = 0; d < 64; ++d) w[d] = wr[d];
            #pragma unroll
            for (int r = 0; r < RR; ++r) {
                #pragma unroll
                for (int d = 0; d < 64; ++d)
                    acc[r] += s_a1[r * 256 + kc * 64 + d] * w[d];
            }
        }
        #pragma unroll
        for (int r = 0; r < RR; ++r)
            s_a2[r * 257 + tid] = fmaxf(acc[r], 0.f);
    }
    __syncthreads();

    // ---- layer 3 + sigmoid: out[r][o], threads 0..RR*8-1 ----
    if (tid < RR * 8) {
        int r = tid >> 3, o = tid & 7;
        float acc = l3_b[o];
        const float* wr = l3_w + o * 256;
        #pragma unroll 8
        for (int k = 0; k < 256; ++k)
            acc += s_a2[r * 257 + k] * wr[k];
        out[(size_t)(b0 + r) * 8 + o] = 1.f / (1.f + expf(-acc));  // MAX_ACTION=1
    }
}

// ---------------------------------------------------------------------------
extern "C" void kernel_launch(void* const* d_in, const int* in_sizes, int n_in,
                              void* d_out, int out_size, void* d_ws, size_t ws_size,
                              hipStream_t stream)
{
    const float* gs    = (const float*)d_in[0];
    const float* ls    = (const float*)d_in[1];
    const float* W_w   = (const float*)d_in[2];
    const float* W_b   = (const float*)d_in[3];
    const float* U_w   = (const float*)d_in[4];
    const float* U_b   = (const float*)d_in[5];
    const float* att_w = (const float*)d_in[6];
    const float* att_b = (const float*)d_in[7];
    const float* l1_w  = (const float*)d_in[8];
    const float* l1_b  = (const float*)d_in[9];
    const float* l2_w  = (const float*)d_in[10];
    const float* l2_b  = (const float*)d_in[11];
    const float* l3_w  = (const float*)d_in[12];
    const float* l3_b  = (const float*)d_in[13];

    float* states = (float*)d_ws;            // B*64 floats = 1 MB scratch
    float* out    = (float*)d_out;

    stage1_kernel<<<BB, 256, 0, stream>>>(gs, ls, W_w, W_b, U_w, U_b,
                                          att_w, att_b, states);
    mlp_kernel<<<BB / RR, 256, 0, stream>>>(states, l1_w, l1_b, l2_w, l2_b,
                                            l3_w, l3_b, out);
}

// Round 2
// 365.567 us; speedup vs baseline: 1.1239x; 1.1239x over previous
//
#include <hip/hip_runtime.h>
#include <math.h>

#define BB 4096
#define LL 200
#define HH 32
#define RR 4       // rows per block in MLP kernel

// ---------------------------------------------------------------------------
// Stage 1 (algebraically collapsed):
//   c   = U_w^T a_l                      (64-vec, b-independent)
//   d_l = x[l].c + U_b.a_l + gt + att_b  -> sl = leaky(d_l)
//   y   = sum_l sl*x[l],  S = sum_l sl
//   V[h]= U_w[h].y + U_b[h]*S
//   states[b] = relu(concat(n0*wg, V/total))
// One WAVE per b; 16-lane groups own one l each; no __syncthreads in hot loop.
// ---------------------------------------------------------------------------
__global__ __launch_bounds__(256) void stage1_kernel(
    const float* __restrict__ gs,
    const float* __restrict__ ls,
    const float* __restrict__ W_w,
    const float* __restrict__ W_b,
    const float* __restrict__ U_w,
    const float* __restrict__ U_b,
    const float* __restrict__ att_w,
    const float* __restrict__ att_b,
    float* __restrict__ states)
{
    __shared__ float c_lds[4 * 64];
    __shared__ float y_lds[4 * 64];

    const int tid  = threadIdx.x;
    const int lane = tid & 63;
    const int wid  = tid >> 6;
    const int b    = blockIdx.x * 4 + wid;

    const int h    = lane & 31;   // owned hidden unit (both halves)
    const int half = lane >> 5;   // d-half for 64-d dots
    const int q    = lane & 15;   // d-quad within l-group
    const int lg   = lane >> 4;   // l-group 0..3

    // ---- wg[h] = gs[b].W_w[h] + W_b[h]; halves split d, xor32 combine ----
    const float4* g4 = (const float4*)(gs + (size_t)b * 64);
    const float4* W4 = (const float4*)(W_w);
    float wg = (half == 0) ? W_b[h] : 0.f;
    #pragma unroll
    for (int dd = 0; dd < 8; ++dd) {
        float4 gv = g4[half * 8 + dd];
        float4 wv = W4[h * 16 + half * 8 + dd];
        wg += gv.x * wv.x + gv.y * wv.y + gv.z * wv.z + gv.w * wv.w;
    }
    wg += __shfl_xor(wg, 32);     // all lanes now hold wg[h]

    // ---- gt = wg.a_g ; t2 = wg.a_l  (butterfly over h within 32-halves) ----
    float gt = wg * att_w[h];
    float t2 = wg * att_w[HH + h];
    #pragma unroll
    for (int m = 1; m < 32; m <<= 1) {
        gt += __shfl_xor(gt, m);
        t2 += __shfl_xor(t2, m);
    }
    const float attb = att_b[0];
    const float lin0 = gt + t2 + attb;
    const float s0   = (lin0 > 0.f) ? lin0 : 0.01f * lin0;

    // ---- c[d] = sum_h a_l[h]*U_w[h][d] (lane owns d=lane); ubal uniform ----
    float c = 0.f;
    float ubal = 0.f;
    #pragma unroll
    for (int hh = 0; hh < HH; ++hh) {
        const float alh = att_w[HH + hh];        // uniform -> s_load
        c    += alh * U_w[hh * 64 + lane];       // coalesced, L1-hot
        ubal += alh * U_b[hh];
    }
    c_lds[wid * 64 + lane] = c;
    __syncthreads();
    const float4 cq = *(const float4*)&c_lds[wid * 64 + 4 * q];
    const float base = gt + ubal + attb;

    // ---- main stream: 50 chunks x 4 l's, depth-2 prefetch ----
    const float4* xs = (const float4*)(ls + (size_t)b * (LL * 64));
    const int idx0 = lg * 16 + q;
    float4 yx = make_float4(0.f, 0.f, 0.f, 0.f);
    float Sacc = 0.f;
    float4 X0 = xs[idx0];
    float4 X1 = xs[idx0 + 64];
    #pragma unroll 2
    for (int t = 0; t < 50; ++t) {
        float4 X = X0;
        X0 = X1;
        const int tn = (t + 2 < 50) ? (t + 2) : 49;   // clamped redundant tail
        X1 = xs[idx0 + tn * 64];

        float p = X.x * cq.x + X.y * cq.y + X.z * cq.z + X.w * cq.w;
        p += __shfl_xor(p, 1);
        p += __shfl_xor(p, 2);
        p += __shfl_xor(p, 4);
        p += __shfl_xor(p, 8);        // 16-lane group dot: x[l].c
        const float linv = p + base;
        const float sl = (linv > 0.f) ? linv : 0.01f * linv;
        yx.x += sl * X.x;
        yx.y += sl * X.y;
        yx.z += sl * X.z;
        yx.w += sl * X.w;
        Sacc += sl;                   // identical across the 16-lane group
    }

    // ---- combine the 4 l-groups (masks 16,32 only) ----
    #pragma unroll
    for (int m = 16; m < 64; m <<= 1) {
        yx.x += __shfl_xor(yx.x, m);
        yx.y += __shfl_xor(yx.y, m);
        yx.z += __shfl_xor(yx.z, m);
        yx.w += __shfl_xor(yx.w, m);
        Sacc += __shfl_xor(Sacc, m);
    }
    if (lane < 16) *(float4*)&y_lds[wid * 64 + 4 * q] = yx;
    __syncthreads();

    // ---- V[h] = U_w[h].y + U_b[h]*S ----
    float V = (half == 0) ? (U_b[h] * Sacc) : 0.f;
    const float4* U4 = (const float4*)U_w;
    const float4* y4 = (const float4*)&y_lds[wid * 64];
    #pragma unroll
    for (int dd = 0; dd < 8; ++dd) {
        float4 uv = U4[h * 16 + half * 8 + dd];
        float4 yv = y4[half * 8 + dd];
        V += uv.x * yv.x + uv.y * yv.y + uv.z * yv.z + uv.w * yv.w;
    }
    V += __shfl_xor(V, 32);           // all lanes hold full V[h]

    const float total = s0 + Sacc;
    const float n0    = s0 / total;
    const float outv  = (lane < 32) ? (n0 * wg) : (V / total);
    states[(size_t)b * 64 + lane] = fmaxf(outv, 0.f);
}

// ---------------------------------------------------------------------------
// Stage 2: fused MLP 64 -> 256 -> 256 -> 8 with relu/relu/sigmoid.
// RR rows per block; thread j owns hidden unit j (weight row in VGPRs,
// activations broadcast from LDS).
// ---------------------------------------------------------------------------
__global__ __launch_bounds__(256) void mlp_kernel(
    const float* __restrict__ states,
    const float* __restrict__ l1_w, const float* __restrict__ l1_b,
    const float* __restrict__ l2_w, const float* __restrict__ l2_b,
    const float* __restrict__ l3_w, const float* __restrict__ l3_b,
    float* __restrict__ out)
{
    __shared__ __align__(16) float s_x [RR * 64];
    __shared__ __align__(16) float s_a1[RR * 256];
    __shared__ float s_a2[RR * 257];   // pad 257 -> conflict-free layer-3 reads

    const int tid = threadIdx.x;
    const int b0  = blockIdx.x * RR;

    const float4* st4 = (const float4*)(states + (size_t)b0 * 64);
    if (tid < RR * 16) ((float4*)s_x)[tid] = st4[tid];
    __syncthreads();

    float w[64];

    // ---- layer 1 ----
    {
        const float* wr = l1_w + tid * 64;
        #pragma unroll
        for (int d = 0; d < 64; ++d) w[d] = wr[d];
        float bias = l1_b[tid];
        #pragma unroll
        for (int r = 0; r < RR; ++r) {
            float acc = bias;
            #pragma unroll
            for (int d = 0; d < 64; ++d)
                acc += s_x[r * 64 + d] * w[d];
            s_a1[r * 256 + tid] = fmaxf(acc, 0.f);
        }
    }
    __syncthreads();

    // ---- layer 2 ----
    {
        float acc[RR];
        float bias = l2_b[tid];
        #pragma unroll
        for (int r = 0; r < RR; ++r) acc[r] = bias;
        for (int kc = 0; kc < 4; ++kc) {
            const float* wr = l2_w + tid * 256 + kc * 64;
            #pragma unroll
            for (int d = 0; d < 64; ++d) w[d] = wr[d];
            #pragma unroll
            for (int r = 0; r < RR; ++r) {
                #pragma unroll
                for (int d = 0; d < 64; ++d)
                    acc[r] += s_a1[r * 256 + kc * 64 + d] * w[d];
            }
        }
        #pragma unroll
        for (int r = 0; r < RR; ++r)
            s_a2[r * 257 + tid] = fmaxf(acc[r], 0.f);
    }
    __syncthreads();

    // ---- layer 3 + sigmoid ----
    if (tid < RR * 8) {
        int r = tid >> 3, o = tid & 7;
        float acc = l3_b[o];
        const float* wr = l3_w + o * 256;
        #pragma unroll 8
        for (int k = 0; k < 256; ++k)
            acc += s_a2[r * 257 + k] * wr[k];
        out[(size_t)(b0 + r) * 8 + o] = 1.f / (1.f + expf(-acc));  // MAX_ACTION=1
    }
}

// ---------------------------------------------------------------------------
extern "C" void kernel_launch(void* const* d_in, const int* in_sizes, int n_in,
                              void* d_out, int out_size, void* d_ws, size_t ws_size,
                              hipStream_t stream)
{
    const float* gs    = (const float*)d_in[0];
    const float* ls    = (const float*)d_in[1];
    const float* W_w   = (const float*)d_in[2];
    const float* W_b   = (const float*)d_in[3];
    const float* U_w   = (const float*)d_in[4];
    const float* U_b   = (const float*)d_in[5];
    const float* att_w = (const float*)d_in[6];
    const float* att_b = (const float*)d_in[7];
    const float* l1_w  = (const float*)d_in[8];
    const float* l1_b  = (const float*)d_in[9];
    const float* l2_w  = (const float*)d_in[10];
    const float* l2_b  = (const float*)d_in[11];
    const float* l3_w  = (const float*)d_in[12];
    const float* l3_b  = (const float*)d_in[13];

    float* states = (float*)d_ws;            // B*64 floats = 1 MB scratch
    float* out    = (float*)d_out;

    stage1_kernel<<<BB / 4, 256, 0, stream>>>(gs, ls, W_w, W_b, U_w, U_b,
                                              att_w, att_b, states);
    mlp_kernel<<<BB / RR, 256, 0, stream>>>(states, l1_w, l1_b, l2_w, l2_b,
                                            l3_w, l3_b, out);
}

// Round 3
// 364.222 us; speedup vs baseline: 1.1280x; 1.0037x over previous
//
#include <hip/hip_runtime.h>
#include <math.h>

#define BB 4096
#define LL 200
#define HH 32

// ---------------------------------------------------------------------------
// Fully fused actor forward. One 256-thread block handles 4 batch rows:
//   Phase A (per wave, wave w owns b = blk*4+w; no cross-wave deps):
//     collapsed attention-pooling:
//       c    = U_w^T a_l                       (b-independent 64-vec)
//       sl_l = leaky(x[l].c + U_b.a_l + gt + att_b)
//       y    = sum_l sl*x[l],  S = sum_l sl
//       V[h] = U_w[h].y + U_b[h]*S
//       states = relu(concat(n0*wg, V/total))  -> LDS
//   Phase B (block-wide): MLP 64->256->256->8, relu/relu/sigmoid, RR=4 rows.
// Phase A is a pure coalesced HBM stream (210 MB total across grid, the
// roofline floor); Phase B is VALU+L2 and overlaps phase A of other blocks.
// ---------------------------------------------------------------------------
__global__ __launch_bounds__(256) void actor_fused_kernel(
    const float* __restrict__ gs,
    const float* __restrict__ ls,
    const float* __restrict__ W_w, const float* __restrict__ W_b,
    const float* __restrict__ U_w, const float* __restrict__ U_b,
    const float* __restrict__ att_w, const float* __restrict__ att_b,
    const float* __restrict__ l1_w, const float* __restrict__ l1_b,
    const float* __restrict__ l2_w, const float* __restrict__ l2_b,
    const float* __restrict__ l3_w, const float* __restrict__ l3_b,
    float* __restrict__ out)
{
    __shared__ float c_lds[4 * 64];
    __shared__ float y_lds[4 * 64];
    __shared__ __align__(16) float s_x [4 * 64];
    __shared__ __align__(16) float s_a1[4 * 256];
    __shared__ __align__(16) float s_a2[4 * 260];  // pad 260: float4-able, conflict-free

    const int tid  = threadIdx.x;
    const int lane = tid & 63;
    const int wid  = tid >> 6;
    const int b    = blockIdx.x * 4 + wid;

    const int h    = lane & 31;   // owned hidden unit (both halves)
    const int half = lane >> 5;   // d-half for 64-d dots
    const int q    = lane & 15;   // d-quad within l-group
    const int lg   = lane >> 4;   // l-group 0..3

    // ================= Phase A: attention pooling (per wave) =================

    // ---- wg[h] = gs[b].W_w[h] + W_b[h]; halves split d, xor32 combine ----
    const float4* g4 = (const float4*)(gs + (size_t)b * 64);
    const float4* W4 = (const float4*)(W_w);
    float wg = (half == 0) ? W_b[h] : 0.f;
    #pragma unroll
    for (int dd = 0; dd < 8; ++dd) {
        float4 gv = g4[half * 8 + dd];
        float4 wv = W4[h * 16 + half * 8 + dd];
        wg += gv.x * wv.x + gv.y * wv.y + gv.z * wv.z + gv.w * wv.w;
    }
    wg += __shfl_xor(wg, 32);     // all lanes now hold wg[h]

    // ---- gt = wg.a_g ; t2 = wg.a_l (butterfly over h within 32-halves) ----
    float gt = wg * att_w[h];
    float t2 = wg * att_w[HH + h];
    #pragma unroll
    for (int m = 1; m < 32; m <<= 1) {
        gt += __shfl_xor(gt, m);
        t2 += __shfl_xor(t2, m);
    }
    const float attb = att_b[0];
    const float lin0 = gt + t2 + attb;
    const float s0   = (lin0 > 0.f) ? lin0 : 0.01f * lin0;

    // ---- c[d] = sum_h a_l[h]*U_w[h][d]  (lane owns d=lane) ----
    float c = 0.f;
    float ubal = 0.f;
    #pragma unroll
    for (int hh = 0; hh < HH; ++hh) {
        const float alh = att_w[HH + hh];        // uniform -> s_load
        c    += alh * U_w[hh * 64 + lane];       // coalesced, L1-hot
        ubal += alh * U_b[hh];
    }
    c_lds[wid * 64 + lane] = c;
    __syncthreads();
    const float4 cq = *(const float4*)&c_lds[wid * 64 + 4 * q];
    const float base = gt + ubal + attb;

    // ---- main stream: 50 chunks x 4 rows, depth-2 prefetch, coalesced ----
    const float4* xs = (const float4*)(ls + (size_t)b * (LL * 64));
    const int idx0 = lg * 16 + q;
    float4 yx = make_float4(0.f, 0.f, 0.f, 0.f);
    float Sacc = 0.f;
    float4 X0 = xs[idx0];
    float4 X1 = xs[idx0 + 64];
    #pragma unroll 2
    for (int t = 0; t < 50; ++t) {
        float4 X = X0;
        X0 = X1;
        const int tn = (t + 2 < 50) ? (t + 2) : 49;   // clamped redundant tail
        X1 = xs[idx0 + tn * 64];

        float p = X.x * cq.x + X.y * cq.y + X.z * cq.z + X.w * cq.w;
        p += __shfl_xor(p, 1);
        p += __shfl_xor(p, 2);
        p += __shfl_xor(p, 4);
        p += __shfl_xor(p, 8);        // 16-lane group dot: x[l].c
        const float linv = p + base;
        const float sl = (linv > 0.f) ? linv : 0.01f * linv;
        yx.x += sl * X.x;
        yx.y += sl * X.y;
        yx.z += sl * X.z;
        yx.w += sl * X.w;
        Sacc += sl;                   // identical across the 16-lane group
    }

    // ---- combine the 4 l-groups ----
    #pragma unroll
    for (int m = 16; m < 64; m <<= 1) {
        yx.x += __shfl_xor(yx.x, m);
        yx.y += __shfl_xor(yx.y, m);
        yx.z += __shfl_xor(yx.z, m);
        yx.w += __shfl_xor(yx.w, m);
        Sacc += __shfl_xor(Sacc, m);
    }
    if (lane < 16) *(float4*)&y_lds[wid * 64 + 4 * q] = yx;
    __syncthreads();

    // ---- V[h] = U_w[h].y + U_b[h]*S ----
    float V = (half == 0) ? (U_b[h] * Sacc) : 0.f;
    const float4* U4 = (const float4*)U_w;
    const float4* y4 = (const float4*)&y_lds[wid * 64];
    #pragma unroll
    for (int dd = 0; dd < 8; ++dd) {
        float4 uv = U4[h * 16 + half * 8 + dd];
        float4 yv = y4[half * 8 + dd];
        V += uv.x * yv.x + uv.y * yv.y + uv.z * yv.z + uv.w * yv.w;
    }
    V += __shfl_xor(V, 32);           // all lanes hold full V[h]

    const float total = s0 + Sacc;
    const float n0    = s0 / total;
    const float outv  = (lane < 32) ? (n0 * wg) : (V / total);
    s_x[wid * 64 + lane] = fmaxf(outv, 0.f);   // states -> LDS (no global trip)
    __syncthreads();

    // ================= Phase B: MLP 64->256->256->8 (block-wide) =============

    float w[64];

    // ---- layer 1: thread owns unit tid; weight row in VGPRs ----
    {
        const float* wr = l1_w + tid * 64;
        #pragma unroll
        for (int d = 0; d < 64; ++d) w[d] = wr[d];
        float bias = l1_b[tid];
        #pragma unroll
        for (int r = 0; r < 4; ++r) {
            float acc = bias;
            #pragma unroll
            for (int d = 0; d < 64; ++d)
                acc += s_x[r * 64 + d] * w[d];   // LDS broadcast
            s_a1[r * 256 + tid] = fmaxf(acc, 0.f);
        }
    }
    __syncthreads();

    // ---- layer 2 ----
    {
        float acc[4];
        float bias = l2_b[tid];
        #pragma unroll
        for (int r = 0; r < 4; ++r) acc[r] = bias;
        for (int kc = 0; kc < 4; ++kc) {
            const float* wr = l2_w + tid * 256 + kc * 64;
            #pragma unroll
            for (int d = 0; d < 64; ++d) w[d] = wr[d];
            #pragma unroll
            for (int r = 0; r < 4; ++r) {
                #pragma unroll
                for (int d = 0; d < 64; ++d)
                    acc[r] += s_a1[r * 256 + kc * 64 + d] * w[d];
            }
        }
        #pragma unroll
        for (int r = 0; r < 4; ++r)
            s_a2[r * 260 + tid] = fmaxf(acc[r], 0.f);
    }
    __syncthreads();

    // ---- layer 3 + sigmoid: threads 0..31, float4 LDS reads ----
    if (tid < 32) {
        int r = tid >> 3, o = tid & 7;
        float acc = l3_b[o];
        const float4* wr4 = (const float4*)(l3_w + o * 256);
        const float4* a4  = (const float4*)&s_a2[r * 260];
        #pragma unroll 8
        for (int k = 0; k < 64; ++k) {
            float4 av = a4[k];
            float4 wv = wr4[k];
            acc += av.x * wv.x + av.y * wv.y + av.z * wv.z + av.w * wv.w;
        }
        out[(size_t)(blockIdx.x * 4 + r) * 8 + o] =
            1.f / (1.f + __expf(-acc));   // MAX_ACTION = 1
    }
}

// ---------------------------------------------------------------------------
extern "C" void kernel_launch(void* const* d_in, const int* in_sizes, int n_in,
                              void* d_out, int out_size, void* d_ws, size_t ws_size,
                              hipStream_t stream)
{
    const float* gs    = (const float*)d_in[0];
    const float* ls    = (const float*)d_in[1];
    const float* W_w   = (const float*)d_in[2];
    const float* W_b   = (const float*)d_in[3];
    const float* U_w   = (const float*)d_in[4];
    const float* U_b   = (const float*)d_in[5];
    const float* att_w = (const float*)d_in[6];
    const float* att_b = (const float*)d_in[7];
    const float* l1_w  = (const float*)d_in[8];
    const float* l1_b  = (const float*)d_in[9];
    const float* l2_w  = (const float*)d_in[10];
    const float* l2_b  = (const float*)d_in[11];
    const float* l3_w  = (const float*)d_in[12];
    const float* l3_b  = (const float*)d_in[13];

    actor_fused_kernel<<<BB / 4, 256, 0, stream>>>(
        gs, ls, W_w, W_b, U_w, U_b, att_w, att_b,
        l1_w, l1_b, l2_w, l2_b, l3_w, l3_b, (float*)d_out);
}

// Round 4
// 357.335 us; speedup vs baseline: 1.1498x; 1.0193x over previous
//
#include <hip/hip_runtime.h>
#include <math.h>

#define BB 4096
#define LL 200
#define HH 32
#define PF 8      // prefetch depth (outstanding global loads per wave)

// ---------------------------------------------------------------------------
// Fully fused actor forward. One 256-thread block handles 4 batch rows:
//   Phase A (per wave, wave w owns b = blk*4+w):
//     collapsed attention-pooling:
//       c    = U_w^T a_l                       (b-independent 64-vec)
//       sl_l = leaky(x[l].c + U_b.a_l + gt + att_b)
//       y    = sum_l sl*x[l],  S = sum_l sl
//       V[h] = U_w[h].y + U_b[h]*S
//       states = relu(concat(n0*wg, V/total))  -> LDS
//   Phase B (block-wide): MLP 64->256->256->8, relu/relu/sigmoid.
// R3 post-mortem: depth-2 prefetch left the stream latency-bound
// (780 GB/s, VALUBusy 15%). PF=8 ring buffer + full unroll fixes the
// memory-level parallelism (Little's law: 8 KB in flight/wave).
// ---------------------------------------------------------------------------
__global__ __launch_bounds__(256) void actor_fused_kernel(
    const float* __restrict__ gs,
    const float* __restrict__ ls,
    const float* __restrict__ W_w, const float* __restrict__ W_b,
    const float* __restrict__ U_w, const float* __restrict__ U_b,
    const float* __restrict__ att_w, const float* __restrict__ att_b,
    const float* __restrict__ l1_w, const float* __restrict__ l1_b,
    const float* __restrict__ l2_w, const float* __restrict__ l2_b,
    const float* __restrict__ l3_w, const float* __restrict__ l3_b,
    float* __restrict__ out)
{
    __shared__ float c_lds[4 * 64];
    __shared__ float y_lds[4 * 64];
    __shared__ __align__(16) float s_x [4 * 64];
    __shared__ __align__(16) float s_a1[4 * 256];
    __shared__ __align__(16) float s_a2[4 * 260];  // pad 260: float4-able, conflict-free

    const int tid  = threadIdx.x;
    const int lane = tid & 63;
    const int wid  = tid >> 6;
    const int b    = blockIdx.x * 4 + wid;

    const int h    = lane & 31;   // owned hidden unit (both halves)
    const int half = lane >> 5;   // d-half for 64-d dots
    const int q    = lane & 15;   // d-quad within l-group
    const int lg   = lane >> 4;   // l-group 0..3

    // ================= Phase A: attention pooling (per wave) =================

    // ---- wg[h] = gs[b].W_w[h] + W_b[h]; halves split d, xor32 combine ----
    const float4* g4 = (const float4*)(gs + (size_t)b * 64);
    const float4* W4 = (const float4*)(W_w);
    float wg = (half == 0) ? W_b[h] : 0.f;
    #pragma unroll
    for (int dd = 0; dd < 8; ++dd) {
        float4 gv = g4[half * 8 + dd];
        float4 wv = W4[h * 16 + half * 8 + dd];
        wg += gv.x * wv.x + gv.y * wv.y + gv.z * wv.z + gv.w * wv.w;
    }
    wg += __shfl_xor(wg, 32);     // all lanes now hold wg[h]

    // ---- gt = wg.a_g ; t2 = wg.a_l (butterfly over h within 32-halves) ----
    float gt = wg * att_w[h];
    float t2 = wg * att_w[HH + h];
    #pragma unroll
    for (int m = 1; m < 32; m <<= 1) {
        gt += __shfl_xor(gt, m);
        t2 += __shfl_xor(t2, m);
    }
    const float attb = att_b[0];
    const float lin0 = gt + t2 + attb;
    const float s0   = (lin0 > 0.f) ? lin0 : 0.01f * lin0;

    // ---- c[d] = sum_h a_l[h]*U_w[h][d]  (lane owns d=lane) ----
    float c = 0.f;
    float ubal = 0.f;
    #pragma unroll
    for (int hh = 0; hh < HH; ++hh) {
        const float alh = att_w[HH + hh];        // uniform -> s_load
        c    += alh * U_w[hh * 64 + lane];       // coalesced, L1-hot
        ubal += alh * U_b[hh];
    }
    c_lds[wid * 64 + lane] = c;
    __syncthreads();
    const float4 cq = *(const float4*)&c_lds[wid * 64 + 4 * q];
    const float base = gt + ubal + attb;

    // ---- main stream: 50 chunks x 4 rows, depth-PF ring prefetch ----
    const float4* xs = (const float4*)(ls + (size_t)b * (LL * 64));
    const int idx0 = lg * 16 + q;
    float4 yx = make_float4(0.f, 0.f, 0.f, 0.f);
    float Sacc = 0.f;

    float4 Xbuf[PF];
    #pragma unroll
    for (int i = 0; i < PF; ++i)
        Xbuf[i] = xs[idx0 + i * 64];

    #pragma unroll                 // FULL unroll: ring index compile-time,
    for (int t = 0; t < 50; ++t) { // buffer lives in VGPRs, vmcnt(PF-1) waits
        float4 X = Xbuf[t & (PF - 1)];
        int tn = t + PF;
        if (tn > 49) tn = 49;      // clamped redundant tail (L1-hot)
        Xbuf[t & (PF - 1)] = xs[idx0 + tn * 64];

        float p = X.x * cq.x + X.y * cq.y + X.z * cq.z + X.w * cq.w;
        p += __shfl_xor(p, 1);
        p += __shfl_xor(p, 2);
        p += __shfl_xor(p, 4);
        p += __shfl_xor(p, 8);     // 16-lane group dot: x[l].c
        const float linv = p + base;
        const float sl = (linv > 0.f) ? linv : 0.01f * linv;
        yx.x += sl * X.x;
        yx.y += sl * X.y;
        yx.z += sl * X.z;
        yx.w += sl * X.w;
        Sacc += sl;                // identical across the 16-lane group
    }

    // ---- combine the 4 l-groups ----
    #pragma unroll
    for (int m = 16; m < 64; m <<= 1) {
        yx.x += __shfl_xor(yx.x, m);
        yx.y += __shfl_xor(yx.y, m);
        yx.z += __shfl_xor(yx.z, m);
        yx.w += __shfl_xor(yx.w, m);
        Sacc += __shfl_xor(Sacc, m);
    }
    if (lane < 16) *(float4*)&y_lds[wid * 64 + 4 * q] = yx;
    __syncthreads();

    // ---- V[h] = U_w[h].y + U_b[h]*S ----
    float V = (half == 0) ? (U_b[h] * Sacc) : 0.f;
    const float4* U4 = (const float4*)U_w;
    const float4* y4 = (const float4*)&y_lds[wid * 64];
    #pragma unroll
    for (int dd = 0; dd < 8; ++dd) {
        float4 uv = U4[h * 16 + half * 8 + dd];
        float4 yv = y4[half * 8 + dd];
        V += uv.x * yv.x + uv.y * yv.y + uv.z * yv.z + uv.w * yv.w;
    }
    V += __shfl_xor(V, 32);        // all lanes hold full V[h]

    const float total = s0 + Sacc;
    const float n0    = s0 / total;
    const float outv  = (lane < 32) ? (n0 * wg) : (V / total);
    s_x[wid * 64 + lane] = fmaxf(outv, 0.f);   // states -> LDS
    __syncthreads();

    // ================= Phase B: MLP 64->256->256->8 (block-wide) =============

    float w[64];

    // ---- layer 1: thread owns unit tid; weight row in VGPRs ----
    {
        const float* wr = l1_w + tid * 64;
        #pragma unroll
        for (int d = 0; d < 64; ++d) w[d] = wr[d];
        float bias = l1_b[tid];
        #pragma unroll
        for (int r = 0; r < 4; ++r) {
            float acc = bias;
            #pragma unroll
            for (int d = 0; d < 64; ++d)
                acc += s_x[r * 64 + d] * w[d];   // LDS broadcast
            s_a1[r * 256 + tid] = fmaxf(acc, 0.f);
        }
    }
    __syncthreads();

    // ---- layer 2 ----
    {
        float acc[4];
        float bias = l2_b[tid];
        #pragma unroll
        for (int r = 0; r < 4; ++r) acc[r] = bias;
        for (int kc = 0; kc < 4; ++kc) {
            const float* wr = l2_w + tid * 256 + kc * 64;
            #pragma unroll
            for (int d = 0; d < 64; ++d) w[d] = wr[d];
            #pragma unroll
            for (int r = 0; r < 4; ++r) {
                #pragma unroll
                for (int d = 0; d < 64; ++d)
                    acc[r] += s_a1[r * 256 + kc * 64 + d] * w[d];
            }
        }
        #pragma unroll
        for (int r = 0; r < 4; ++r)
            s_a2[r * 260 + tid] = fmaxf(acc[r], 0.f);
    }
    __syncthreads();

    // ---- layer 3 + sigmoid: threads 0..31, float4 LDS reads ----
    if (tid < 32) {
        int r = tid >> 3, o = tid & 7;
        float acc = l3_b[o];
        const float4* wr4 = (const float4*)(l3_w + o * 256);
        const float4* a4  = (const float4*)&s_a2[r * 260];
        #pragma unroll 8
        for (int k = 0; k < 64; ++k) {
            float4 av = a4[k];
            float4 wv = wr4[k];
            acc += av.x * wv.x + av.y * wv.y + av.z * wv.z + av.w * wv.w;
        }
        out[(size_t)(blockIdx.x * 4 + r) * 8 + o] =
            1.f / (1.f + __expf(-acc));   // MAX_ACTION = 1
    }
}

// ---------------------------------------------------------------------------
extern "C" void kernel_launch(void* const* d_in, const int* in_sizes, int n_in,
                              void* d_out, int out_size, void* d_ws, size_t ws_size,
                              hipStream_t stream)
{
    const float* gs    = (const float*)d_in[0];
    const float* ls    = (const float*)d_in[1];
    const float* W_w   = (const float*)d_in[2];
    const float* W_b   = (const float*)d_in[3];
    const float* U_w   = (const float*)d_in[4];
    const float* U_b   = (const float*)d_in[5];
    const float* att_w = (const float*)d_in[6];
    const float* att_b = (const float*)d_in[7];
    const float* l1_w  = (const float*)d_in[8];
    const float* l1_b  = (const float*)d_in[9];
    const float* l2_w  = (const float*)d_in[10];
    const float* l2_b  = (const float*)d_in[11];
    const float* l3_w  = (const float*)d_in[12];
    const float* l3_b  = (const float*)d_in[13];

    actor_fused_kernel<<<BB / 4, 256, 0, stream>>>(
        gs, ls, W_w, W_b, U_w, U_b, att_w, att_b,
        l1_w, l1_b, l2_w, l2_b, l3_w, l3_b, (float*)d_out);
}